// Round 6
// baseline (484.620 us; speedup 1.0000x reference)
//
#include <hip/hip_runtime.h>
#include <hip/hip_bf16.h>
#include <math.h>

// Problem constants (B=2, S=2048, D=1024, H=16, DH=64)
#define BB 2
#define SS 2048
#define DD 1024
#define HH 16
#define DH 64
#define NTOK (BB * SS)   // 4096
#define LN_EPS 1e-5f
#define BIGNEG -1e30f

typedef __attribute__((ext_vector_type(8))) short bf16x8;   // 8 bf16 = 4 VGPRs
typedef __attribute__((ext_vector_type(4))) float f32x4;    // MFMA accumulator

static __device__ __forceinline__ float b2f(unsigned short u) {
    return __uint_as_float(((unsigned)u) << 16);
}
static __device__ __forceinline__ unsigned short f2bu(float f) {
    __hip_bfloat16 h = __float2bfloat16(f);
    return *(unsigned short*)&h;
}

// async 16B global -> LDS. LDS dest is wave-uniform base + lane*16 by construction.
static __device__ __forceinline__ void async16(const void* g, void* l) {
    __builtin_amdgcn_global_load_lds((const __attribute__((address_space(1))) void*)g,
                                     (__attribute__((address_space(3))) void*)l, 16, 0, 0);
}

// ---------------------------------------------------------------------------
// Merged weight transpose+cast for all 6 weights: one launch, 10240 tiles.
// ---------------------------------------------------------------------------
__global__ __launch_bounds__(256) void transpose_all(const float* __restrict__ Wq,
                                                     const float* __restrict__ Wk,
                                                     const float* __restrict__ Wv,
                                                     const float* __restrict__ Wo,
                                                     const float* __restrict__ W1,
                                                     const float* __restrict__ W2,
                                                     __hip_bfloat16* __restrict__ wqkvt,
                                                     __hip_bfloat16* __restrict__ wot,
                                                     __hip_bfloat16* __restrict__ w1t,
                                                     __hip_bfloat16* __restrict__ w2t) {
    const int bid = blockIdx.x;
    const float* W;
    __hip_bfloat16* Wt;
    int K, N, tile;
    if (bid < 4096) {
        const int m = bid >> 10;
        tile = bid & 1023;
        W = (m == 0) ? Wq : (m == 1) ? Wk : (m == 2) ? Wv : Wo;
        Wt = (m < 3) ? (wqkvt + (size_t)m * 1024 * 1024) : wot;
        K = 1024; N = 1024;
    } else if (bid < 8192) {
        tile = bid - 4096; W = W1; Wt = w1t; K = 1024; N = 4096;
    } else {
        tile = bid - 8192; W = W2; Wt = w2t; K = 2048; N = 1024;
    }
    const int nt = N >> 5;
    const int n0 = (tile % nt) * 32, k0 = (tile / nt) * 32;

    __shared__ float t[32][33];
    const int tx = threadIdx.x & 31, ty = threadIdx.x >> 5;
#pragma unroll
    for (int i = 0; i < 4; ++i)
        t[ty + 8 * i][tx] = W[(size_t)(k0 + ty + 8 * i) * N + n0 + tx];
    __syncthreads();
#pragma unroll
    for (int i = 0; i < 4; ++i)
        Wt[(size_t)(n0 + ty + 8 * i) * K + k0 + tx] = __float2bfloat16(t[tx][ty + 8 * i]);
}

// ---------------------------------------------------------------------------
// LayerNorm fp32 -> bf16. One block per row, D=1024.
// ---------------------------------------------------------------------------
__global__ __launch_bounds__(256) void ln_kernel(const float* __restrict__ x,
                                                 const float* __restrict__ gamma,
                                                 const float* __restrict__ beta,
                                                 __hip_bfloat16* __restrict__ out) {
    const int row = blockIdx.x;
    const int tid = threadIdx.x;
    __shared__ float red[256];

    const float* xp = x + (size_t)row * DD;
    float vals[4];
    float s = 0.f;
#pragma unroll
    for (int i = 0; i < 4; ++i) {
        float v = xp[tid + i * 256];
        vals[i] = v;
        s += v;
    }
    red[tid] = s;
    __syncthreads();
    for (int st = 128; st > 0; st >>= 1) {
        if (tid < st) red[tid] += red[tid + st];
        __syncthreads();
    }
    const float mu = red[0] * (1.0f / DD);
    __syncthreads();
    float sq = 0.f;
#pragma unroll
    for (int i = 0; i < 4; ++i) {
        float d = vals[i] - mu;
        sq += d * d;
    }
    red[tid] = sq;
    __syncthreads();
    for (int st = 128; st > 0; st >>= 1) {
        if (tid < st) red[tid] += red[tid + st];
        __syncthreads();
    }
    const float rinv = rsqrtf(red[0] * (1.0f / DD) + LN_EPS);

    __hip_bfloat16* op = out + (size_t)row * DD;
#pragma unroll
    for (int i = 0; i < 4; ++i) {
        int j = tid + i * 256;
        op[j] = __float2bfloat16(gamma[j] * ((vals[i] - mu) * rinv) + beta[j]);
    }
}

// ---------------------------------------------------------------------------
// MFMA bf16 GEMM (m97 structure): C[M,N] = A[M,K] @ Bt[N,K]^T
// 128x128 tile, 4 waves, BK=64, global_load_lds staging.
// RES: 0 none, 1 add fp32 res[oi].
// EPI: 0 fp32 out, 1 bf16 out,
//      3 qkv-split: cols<2048 -> out (bf16, stride 2048);
//                   cols>=2048 (V) -> res as VT bf16 [1024][4096] transposed.
// ---------------------------------------------------------------------------
template <int RES, int EPI>
__global__ __launch_bounds__(256) void mfma_gemm(const __hip_bfloat16* __restrict__ A,
                                                 const __hip_bfloat16* __restrict__ Bt,
                                                 const void* __restrict__ res,
                                                 void* __restrict__ out,
                                                 int M, int N, int K) {
    __shared__ short As[128 * 64];
    __shared__ short Bs[128 * 64];
    const int tid = threadIdx.x;
    const int lane = tid & 63;
    const int wave = tid >> 6;
    const int row0 = blockIdx.y * 128;
    const int col0 = blockIdx.x * 128;
    const int wr = (wave >> 1) * 64;
    const int wc = (wave & 1) * 64;
    const int l15 = lane & 15;
    const int lk8 = (lane >> 4) * 8;

    f32x4 acc[4][4] = {};

    for (int k0 = 0; k0 < K; k0 += 64) {
#pragma unroll
        for (int r = 0; r < 4; ++r) {
            const int e = (r * 256 + tid) * 8;
            const int ar = e >> 6, ac = e & 63;
            async16(&A[(size_t)(row0 + ar) * K + k0 + ac], &As[e]);
            async16(&Bt[(size_t)(col0 + ar) * K + k0 + ac], &Bs[e]);
        }
        __syncthreads();
#pragma unroll
        for (int kk = 0; kk < 2; ++kk) {
            bf16x8 af[4], bfr[4];
#pragma unroll
            for (int i = 0; i < 4; ++i)
                af[i] = *(const bf16x8*)&As[(wr + i * 16 + l15) * 64 + kk * 32 + lk8];
#pragma unroll
            for (int j = 0; j < 4; ++j)
                bfr[j] = *(const bf16x8*)&Bs[(wc + j * 16 + l15) * 64 + kk * 32 + lk8];
#pragma unroll
            for (int i = 0; i < 4; ++i)
#pragma unroll
                for (int j = 0; j < 4; ++j)
                    acc[i][j] = __builtin_amdgcn_mfma_f32_16x16x32_bf16(af[i], bfr[j], acc[i][j], 0, 0, 0);
        }
        __syncthreads();
    }

    const int r4 = (lane >> 4) * 4;
#pragma unroll
    for (int i = 0; i < 4; ++i) {
#pragma unroll
        for (int j = 0; j < 4; ++j) {
            const int orow0 = row0 + wr + i * 16 + r4;
            const int ocol = col0 + wc + j * 16 + l15;
            if constexpr (EPI == 3) {
                if (ocol < 2048) {
#pragma unroll
                    for (int rg = 0; rg < 4; ++rg)
                        ((__hip_bfloat16*)out)[(size_t)(orow0 + rg) * 2048 + ocol] =
                            __float2bfloat16(acc[i][j][rg]);
                } else {
                    ushort4 u;
                    u.x = f2bu(acc[i][j][0]);
                    u.y = f2bu(acc[i][j][1]);
                    u.z = f2bu(acc[i][j][2]);
                    u.w = f2bu(acc[i][j][3]);
                    *(ushort4*)((unsigned short*)res + (size_t)(ocol - 2048) * 4096 + orow0) = u;
                }
            } else {
#pragma unroll
                for (int rg = 0; rg < 4; ++rg) {
                    const size_t oi = (size_t)(orow0 + rg) * N + ocol;
                    float v = acc[i][j][rg];
                    if constexpr (RES == 1) v += ((const float*)res)[oi];
                    if constexpr (EPI == 0) ((float*)out)[oi] = v;
                    if constexpr (EPI == 1) ((__hip_bfloat16*)out)[oi] = __float2bfloat16(v);
                }
            }
        }
    }
}

// ---------------------------------------------------------------------------
// Fused FFN-in GEMM+GLU: glu[4096,2048] = (A@W1L^T) * sigmoid(A@W1R^T), bf16.
// ---------------------------------------------------------------------------
__global__ __launch_bounds__(256) void mfma_gemm_glu(const __hip_bfloat16* __restrict__ A,
                                                     const __hip_bfloat16* __restrict__ Bt,
                                                     __hip_bfloat16* __restrict__ out) {
    __shared__ short As[128 * 64];
    __shared__ short Bl[128 * 64];
    __shared__ short Br[128 * 64];
    const int tid = threadIdx.x;
    const int lane = tid & 63;
    const int wave = tid >> 6;
    const int row0 = blockIdx.y * 128;
    const int col0 = blockIdx.x * 128;
    const int wr = (wave >> 1) * 64;
    const int wc = (wave & 1) * 64;
    const int l15 = lane & 15;
    const int lk8 = (lane >> 4) * 8;

    f32x4 accl[4][4] = {};
    f32x4 accr[4][4] = {};

    for (int k0 = 0; k0 < 1024; k0 += 64) {
#pragma unroll
        for (int r = 0; r < 4; ++r) {
            const int e = (r * 256 + tid) * 8;
            const int ar = e >> 6, ac = e & 63;
            async16(&A[(size_t)(row0 + ar) * 1024 + k0 + ac], &As[e]);
            async16(&Bt[(size_t)(col0 + ar) * 1024 + k0 + ac], &Bl[e]);
            async16(&Bt[(size_t)(2048 + col0 + ar) * 1024 + k0 + ac], &Br[e]);
        }
        __syncthreads();
#pragma unroll
        for (int kk = 0; kk < 2; ++kk) {
            bf16x8 af[4], bl[4], br[4];
#pragma unroll
            for (int i = 0; i < 4; ++i)
                af[i] = *(const bf16x8*)&As[(wr + i * 16 + l15) * 64 + kk * 32 + lk8];
#pragma unroll
            for (int j = 0; j < 4; ++j) {
                bl[j] = *(const bf16x8*)&Bl[(wc + j * 16 + l15) * 64 + kk * 32 + lk8];
                br[j] = *(const bf16x8*)&Br[(wc + j * 16 + l15) * 64 + kk * 32 + lk8];
            }
#pragma unroll
            for (int i = 0; i < 4; ++i)
#pragma unroll
                for (int j = 0; j < 4; ++j) {
                    accl[i][j] = __builtin_amdgcn_mfma_f32_16x16x32_bf16(af[i], bl[j], accl[i][j], 0, 0, 0);
                    accr[i][j] = __builtin_amdgcn_mfma_f32_16x16x32_bf16(af[i], br[j], accr[i][j], 0, 0, 0);
                }
        }
        __syncthreads();
    }

    const int r4 = (lane >> 4) * 4;
#pragma unroll
    for (int i = 0; i < 4; ++i) {
#pragma unroll
        for (int j = 0; j < 4; ++j) {
#pragma unroll
            for (int rg = 0; rg < 4; ++rg) {
                const int orow = row0 + wr + i * 16 + r4 + rg;
                const int ocol = col0 + wc + j * 16 + l15;
                const float l = accl[i][j][rg];
                const float r = accr[i][j][rg];
                out[(size_t)orow * 2048 + ocol] =
                    __float2bfloat16(l * (1.f / (1.f + __expf(-r))));
            }
        }
    }
}

// ---------------------------------------------------------------------------
// MFMA flash attention v3. 4 waves/block, 16 q/wave (Tq=64), Tk=128 chunks.
// K staged [key][dim] via async16 from qkb; V staged [dim][key] via async16
// from the pre-transposed VT (no in-kernel transpose). Mask folded into an
// additive bias (FMA); causal handled wave-uniformly: tiles fully beyond the
// diagonal are skipped (ktmax), only straddling tiles pay cndmask (ktfull).
// ---------------------------------------------------------------------------
#define PSTR 136
__global__ __launch_bounds__(256, 3) void flash_mfma(const __hip_bfloat16* __restrict__ qkb_,
                                                     const __hip_bfloat16* __restrict__ VT_,
                                                     const int* __restrict__ mask,
                                                     __hip_bfloat16* __restrict__ attnb) {
    const unsigned short* qkb = (const unsigned short*)qkb_;
    const unsigned short* VT = (const unsigned short*)VT_;
    __shared__ __align__(16) short Ks[128 * 64];    // [key][dim]
    __shared__ __align__(16) short Vt[64 * 128];    // [dim][key]
    __shared__ __align__(16) short Ps[4][16 * PSTR];
    __shared__ float bias[128];

    const int tid = threadIdx.x;
    const int lane = tid & 63;
    const int wave = tid >> 6;
    const int l15 = lane & 15;
    const int quad = lane >> 4;
    const int qt = 31 - (blockIdx.x & 31);     // reversed: long blocks first
    const int h = (blockIdx.x >> 5) & 15;
    const int b = blockIdx.x >> 9;
    const int q0 = qt * 64 + wave * 16;        // wave's first query

    // Q fragments (A-layout): m=lane&15 -> query, k=quad*8+j -> dim
    bf16x8 aq[2];
#pragma unroll
    for (int ks = 0; ks < 2; ++ks)
        aq[ks] = *(const bf16x8*)(qkb + (size_t)(b * SS + q0 + l15) * 2048 +
                                  h * 64 + ks * 32 + quad * 8);

    f32x4 O[4];
    float m_r[4], l_r[4];
#pragma unroll
    for (int i = 0; i < 4; ++i) {
        O[i] = (f32x4){0.f, 0.f, 0.f, 0.f};
        m_r[i] = BIGNEG;
        l_r[i] = 0.f;
    }

    const int nch = (qt >> 1) + 1;             // 128-key chunks
    for (int c = 0; c < nch; ++c) {
        const int kb = c * 128;
        __syncthreads();  // protect prev-iter LDS reads before overwrite
        // stage K: 128x64 bf16 (4 rounds x 256 thr x 16B)
#pragma unroll
        for (int r = 0; r < 4; ++r) {
            const int e = r * 256 + tid;
            const int key = e >> 3, dc = e & 7;
            async16(qkb + (size_t)(b * SS + kb + key) * 2048 + 1024 + h * 64 + dc * 8,
                    &Ks[e * 8]);
        }
        // stage V^T: 64 dims x 128 keys from VT (4 rounds x 256 thr x 16B)
#pragma unroll
        for (int r = 0; r < 4; ++r) {
            const int e = r * 256 + tid;
            const int dim = e >> 4, kc = e & 15;
            async16(VT + (size_t)(h * 64 + dim) * 4096 + b * SS + kb + kc * 8,
                    &Vt[e * 8]);
        }
        if (tid < 128) bias[tid] = mask[b * SS + kb + tid] ? 0.f : BIGNEG;
        __syncthreads();

        // wave-uniform causal bounds
        const int dq = q0 - kb;
        int ktmax = ((dq + 15) >> 4) + 1;      // tiles with any valid key
        if (ktmax > 8) ktmax = 8;
        const int ktfull = (dq - 15) >= 0 ? ((dq - 15) >> 4) + 1 : 0;  // no-cndmask tiles

        // ---- S = Q K^T for live tiles
        f32x4 S[8];
#pragma unroll
        for (int kt = 0; kt < 8; ++kt) {
            if (kt >= ktmax) break;
            const bf16x8 bk0 = *(const bf16x8*)&Ks[(kt * 16 + l15) * 64 + quad * 8];
            const bf16x8 bk1 = *(const bf16x8*)&Ks[(kt * 16 + l15) * 64 + 32 + quad * 8];
            f32x4 z = {0.f, 0.f, 0.f, 0.f};
            z = __builtin_amdgcn_mfma_f32_16x16x32_bf16(aq[0], bk0, z, 0, 0, 0);
            S[kt] = __builtin_amdgcn_mfma_f32_16x16x32_bf16(aq[1], bk1, z, 0, 0, 0);
        }
        // ---- scale + mask-bias + (diagonal-only) causal
#pragma unroll
        for (int kt = 0; kt < 8; ++kt) {
            if (kt >= ktmax) break;
            const float bv = bias[kt * 16 + l15];
#pragma unroll
            for (int rg = 0; rg < 4; ++rg) {
                float s = fmaf(S[kt][rg], 0.125f, bv);
                if (kt >= ktfull) {
                    const int key = kb + kt * 16 + l15;
                    const int qrow = q0 + quad * 4 + rg;
                    s = (key <= qrow) ? s : BIGNEG;
                }
                S[kt][rg] = s;
            }
        }
        // ---- online softmax (16-lane row reductions)
        float alpha[4];
#pragma unroll
        for (int rg = 0; rg < 4; ++rg) {
            float v = BIGNEG;
#pragma unroll
            for (int kt = 0; kt < 8; ++kt)
                if (kt < ktmax) v = fmaxf(v, S[kt][rg]);
            v = fmaxf(v, __shfl_xor(v, 1));
            v = fmaxf(v, __shfl_xor(v, 2));
            v = fmaxf(v, __shfl_xor(v, 4));
            v = fmaxf(v, __shfl_xor(v, 8));
            const float mn = fmaxf(m_r[rg], v);
            alpha[rg] = __expf(m_r[rg] - mn);
            m_r[rg] = mn;
            l_r[rg] *= alpha[rg];
        }
#pragma unroll
        for (int kt = 0; kt < 8; ++kt) {
            if (kt >= ktmax) break;
#pragma unroll
            for (int rg = 0; rg < 4; ++rg)
                S[kt][rg] = __expf(S[kt][rg] - m_r[rg]);
        }
#pragma unroll
        for (int rg = 0; rg < 4; ++rg) {
            float v = 0.f;
#pragma unroll
            for (int kt = 0; kt < 8; ++kt)
                if (kt < ktmax) v += S[kt][rg];
            v += __shfl_xor(v, 1);
            v += __shfl_xor(v, 2);
            v += __shfl_xor(v, 4);
            v += __shfl_xor(v, 8);
            l_r[rg] += v;
        }
        // ---- rescale O
#pragma unroll
        for (int nt = 0; nt < 4; ++nt)
#pragma unroll
            for (int rg = 0; rg < 4; ++rg)
                O[nt][rg] *= alpha[rg];
        // ---- P: C-layout regs -> per-wave LDS (A-layout)
        short* Pw = &Ps[wave][0];
#pragma unroll
        for (int kt = 0; kt < 8; ++kt) {
            if (kt >= ktmax) break;
#pragma unroll
            for (int rg = 0; rg < 4; ++rg)
                Pw[(quad * 4 + rg) * PSTR + kt * 16 + l15] = (short)f2bu(S[kt][rg]);
        }
        const int kkmax = (ktmax + 1) >> 1;
        if (ktmax & 1) {   // zero-fill the phantom tile so PV can run in 32-key steps
#pragma unroll
            for (int rg = 0; rg < 4; ++rg)
                Pw[(quad * 4 + rg) * PSTR + ktmax * 16 + l15] = 0;
        }
        asm volatile("s_waitcnt lgkmcnt(0)" ::: "memory");
        // ---- O += P V
#pragma unroll
        for (int kk = 0; kk < 4; ++kk) {
            if (kk >= kkmax) break;
            const bf16x8 ap = *(const bf16x8*)&Pw[l15 * PSTR + kk * 32 + quad * 8];
#pragma unroll
            for (int nt = 0; nt < 4; ++nt) {
                const bf16x8 bv = *(const bf16x8*)&Vt[(nt * 16 + l15) * 128 + kk * 32 + quad * 8];
                O[nt] = __builtin_amdgcn_mfma_f32_16x16x32_bf16(ap, bv, O[nt], 0, 0, 0);
            }
        }
    }

    // epilogue: O /= l, write bf16
#pragma unroll
    for (int rg = 0; rg < 4; ++rg) {
        const int q = q0 + quad * 4 + rg;
        const float inv = 1.f / l_r[rg];
        unsigned short* op = (unsigned short*)attnb + (size_t)(b * SS + q) * 1024 + h * 64;
#pragma unroll
        for (int nt = 0; nt < 4; ++nt)
            op[nt * 16 + l15] = f2bu(O[nt][rg] * inv);
    }
}

// ---------------------------------------------------------------------------
// Launch. Workspace plan (60 MB peak), offsets in bytes:
//   [0,6M)   Wqkv_t bf16 [3072][1024]
//   [6,8M)   Wo_t   bf16 [1024][1024]
//   [8,16M)  W1_t   bf16 [4096][1024]
//   [16,20M) W2_t   bf16 [1024][2048]
//   [20,28M) lnb    bf16 (ln1 then ln2)
//   [28,44M) qkb    bf16 [4096][2048] (q|k)  -> dead after flash
//   [44,52M) VT     bf16 [1024][4096] (v^T)  -> dead after flash
//   [52,60M) attnb  bf16                     -> dead after Wo gemm
//   [28,44M) x1     fp32 (reuses qkb)
//   [44,52M) glub   bf16 (reuses VT)
// ---------------------------------------------------------------------------
extern "C" void kernel_launch(void* const* d_in, const int* in_sizes, int n_in,
                              void* d_out, int out_size, void* d_ws, size_t ws_size,
                              hipStream_t stream) {
    const float* x  = (const float*)d_in[0];
    const int* mask = (const int*)d_in[1];
    const float* Wq = (const float*)d_in[2];
    const float* Wk = (const float*)d_in[3];
    const float* Wv = (const float*)d_in[4];
    const float* Wo = (const float*)d_in[5];
    const float* W1 = (const float*)d_in[6];
    const float* W2 = (const float*)d_in[7];
    const float* g1 = (const float*)d_in[8];
    const float* b1 = (const float*)d_in[9];
    const float* g2 = (const float*)d_in[10];
    const float* b2 = (const float*)d_in[11];

    const size_t MB = 1024 * 1024;
    uint8_t* ws = (uint8_t*)d_ws;
    __hip_bfloat16* wqkvt = (__hip_bfloat16*)(ws);
    __hip_bfloat16* wot   = (__hip_bfloat16*)(ws + 6 * MB);
    __hip_bfloat16* w1t   = (__hip_bfloat16*)(ws + 8 * MB);
    __hip_bfloat16* w2t   = (__hip_bfloat16*)(ws + 16 * MB);
    __hip_bfloat16* lnb   = (__hip_bfloat16*)(ws + 20 * MB);
    __hip_bfloat16* qkb   = (__hip_bfloat16*)(ws + 28 * MB);
    float*          x1    = (float*)(ws + 28 * MB);
    __hip_bfloat16* VT    = (__hip_bfloat16*)(ws + 44 * MB);
    __hip_bfloat16* glub  = (__hip_bfloat16*)(ws + 44 * MB);
    __hip_bfloat16* attnb = (__hip_bfloat16*)(ws + 52 * MB);

    // 0. all weight transposes in one launch
    transpose_all<<<10240, 256, 0, stream>>>(Wq, Wk, Wv, Wo, W1, W2, wqkvt, wot, w1t, w2t);

    // 1. ln1 = LN(x) -> lnb
    ln_kernel<<<NTOK, 256, 0, stream>>>(x, g1, b1, lnb);

    // 2. qkv GEMM: q,k -> qkb; v -> VT (transposed)
    mfma_gemm<0, 3><<<dim3(24, 32), 256, 0, stream>>>(lnb, wqkvt, VT, qkb, NTOK, 3072, 1024);

    // 3. MFMA flash attention -> attnb
    flash_mfma<<<BB * HH * 32, 256, 0, stream>>>(qkb, VT, mask, attnb);

    // 4. x1 = x + attn @ Wo -> x1 (fp32)
    mfma_gemm<1, 0><<<dim3(8, 32), 256, 0, stream>>>(attnb, wot, x, x1, NTOK, 1024, 1024);

    // 5. ln2 = LN(x1) -> lnb
    ln_kernel<<<NTOK, 256, 0, stream>>>(x1, g2, b2, lnb);

    // 6. glu = (ln2@W1L) * sigmoid(ln2@W1R) -> glub
    mfma_gemm_glu<<<dim3(16, 32), 256, 0, stream>>>(lnb, w1t, glub);

    // 7. out = x1 + glu @ W2 -> d_out (fp32)
    mfma_gemm<1, 0><<<dim3(8, 32), 256, 0, stream>>>(glub, w2t, x1, (float*)d_out,
                                                     NTOK, 1024, 2048);
}